// Round 13
// baseline (538.121 us; speedup 1.0000x reference)
//
#include <hip/hip_runtime.h>
#include <stdint.h>
#include <math.h>

// Problem constants
#define N_SEQ 4096
#define EDIM  2048
#define NH    16
#define HD    128

typedef __attribute__((ext_vector_type(8))) short bf16x8;
typedef __attribute__((ext_vector_type(4))) float f32x4;

#define AS1 __attribute__((address_space(1)))
#define AS3 __attribute__((address_space(3)))

__device__ __forceinline__ void gll16(const unsigned short* g, unsigned short* l) {
    __builtin_amdgcn_global_load_lds((const AS1 unsigned int*)g,
                                     (AS3 unsigned int*)l, 16, 0, 0);
}

__device__ __forceinline__ unsigned short f2bf(float f) {
    union { float f; unsigned u; } v; v.f = f;
    unsigned r = v.u + 0x7FFFu + ((v.u >> 16) & 1u);
    return (unsigned short)(r >> 16);
}
__device__ __forceinline__ float bf2f(unsigned short h) {
    union { unsigned u; float f; } v; v.u = ((unsigned)h) << 16;
    return v.f;
}

// ---------------------------------------------------------------- convert x
__global__ void k_convert_x(const float* __restrict__ x,
                            unsigned short* __restrict__ xb, int n4) {
    int i = blockIdx.x * blockDim.x + threadIdx.x;
    int stride = gridDim.x * blockDim.x;
    for (; i < n4; i += stride) {
        float4 v = ((const float4*)x)[i];
        ushort4 o;
        o.x = f2bf(v.x); o.y = f2bf(v.y); o.z = f2bf(v.z); o.w = f2bf(v.w);
        ((ushort4*)xb)[i] = o;
    }
}

// ---------------------------------------------- transpose f32 (RxC) -> bf16 (CxR)
__global__ void k_transpose_f32_bf16(const float* __restrict__ in,
                                     unsigned short* __restrict__ out,
                                     int R, int C) {
    __shared__ unsigned short Ls[64][68];
    const int c0 = blockIdx.x * 64, r0 = blockIdx.y * 64;
    const int t = threadIdx.x;
    #pragma unroll
    for (int i = 0; i < 4; ++i) {
        int ch = i * 256 + t;              // 1024 float4 chunks
        int r = ch >> 4, c4 = (ch & 15) * 4;
        float4 v = *(const float4*)&in[(size_t)(r0 + r) * C + c0 + c4];
        ushort4 o;
        o.x = f2bf(v.x); o.y = f2bf(v.y); o.z = f2bf(v.z); o.w = f2bf(v.w);
        *(ushort4*)&Ls[r][c4] = o;
    }
    __syncthreads();
    #pragma unroll
    for (int i = 0; i < 2; ++i) {
        int ch = i * 256 + t;              // 512 chunks of 8 bf16
        int rr = ch >> 3, c8 = (ch & 7) * 8;
        unsigned short vals[8];
        #pragma unroll
        for (int j = 0; j < 8; ++j) vals[j] = Ls[c8 + j][rr];
        uint4 pk;
        pk.x = (unsigned)vals[0] | ((unsigned)vals[1] << 16);
        pk.y = (unsigned)vals[2] | ((unsigned)vals[3] << 16);
        pk.z = (unsigned)vals[4] | ((unsigned)vals[5] << 16);
        pk.w = (unsigned)vals[6] | ((unsigned)vals[7] << 16);
        *(uint4*)&out[(size_t)(c0 + rr) * R + r0 + c8] = pk;
    }
}

// ---------------------------------------------------------------- bt GEMM (m97)
// C[M,N] = A[M,K] * Bt[N,K]^T  (bf16 in, f32 acc, bf16 or f32 out)
template<int F32OUT>
__launch_bounds__(256, 2)
__global__ void k_gemm_bt(const unsigned short* __restrict__ A,
                          const unsigned short* __restrict__ Bt,
                          void* __restrict__ C,
                          int M, int N, int K) {
    __shared__ unsigned short sh[2 * 128 * 64];   // As | Bs, linear [128][64]
    unsigned short* As = sh;
    unsigned short* Bs = sh + 128 * 64;

    const int t = threadIdx.x;
    const int wave = t >> 6, lane = t & 63;
    const int wm = wave >> 1, wn = wave & 1;
    const int lg = lane >> 4, lr = lane & 15;

    const int nbx = gridDim.x;
    const int nwg = nbx * gridDim.y;
    int bid = blockIdx.y * nbx + blockIdx.x;
    int swz = (bid & 7) * (nwg >> 3) + (bid >> 3);
    const int m0 = (swz / nbx) * 128;
    const int n0 = (swz % nbx) * 128;

    const unsigned short* aptr = A  + (size_t)m0 * K;
    const unsigned short* bptr = Bt + (size_t)n0 * K;

    f32x4 acc[4][4];
    #pragma unroll
    for (int i = 0; i < 4; ++i)
        #pragma unroll
        for (int j = 0; j < 4; ++j) acc[i][j] = f32x4{0.f, 0.f, 0.f, 0.f};

    int schr[4], srow[4], scb[4];
    #pragma unroll
    for (int i = 0; i < 4; ++i) {
        int ch = (i * 4 + wave) * 64 + lane;
        schr[i] = ch;
        srow[i] = ch >> 3;
        scb[i]  = (ch & 7) ^ ((ch >> 3) & 7);
    }

    const int nkb = K >> 6;
    for (int kb = 0; kb < nkb; ++kb) {
        __syncthreads();
        #pragma unroll
        for (int i = 0; i < 4; ++i) {
            const size_t goff = (size_t)srow[i] * K + (size_t)kb * 64 + scb[i] * 8;
            gll16(&aptr[goff], &As[schr[i] * 8]);
            gll16(&bptr[goff], &Bs[schr[i] * 8]);
        }
        __syncthreads();

        #pragma unroll
        for (int kk = 0; kk < 2; ++kk) {
            bf16x8 af[4], bf[4];
            const int cbx = ((kk * 4 + lg) ^ (lr & 7)) * 8;
            #pragma unroll
            for (int i = 0; i < 4; ++i) {
                af[i] = *(const bf16x8*)&As[(wm * 64 + i * 16 + lr) * 64 + cbx];
                bf[i] = *(const bf16x8*)&Bs[(wn * 64 + i * 16 + lr) * 64 + cbx];
            }
            #pragma unroll
            for (int i = 0; i < 4; ++i)
                #pragma unroll
                for (int j = 0; j < 4; ++j)
                    acc[i][j] = __builtin_amdgcn_mfma_f32_16x16x32_bf16(af[i], bf[j], acc[i][j], 0, 0, 0);
        }
    }

    if (F32OUT) {
        #pragma unroll
        for (int i = 0; i < 4; ++i) {
            int row0 = m0 + wm * 64 + i * 16 + lg * 4;
            #pragma unroll
            for (int j = 0; j < 4; ++j) {
                int col = n0 + wn * 64 + j * 16 + lr;
                #pragma unroll
                for (int r = 0; r < 4; ++r)
                    ((float*)C)[(size_t)(row0 + r) * N + col] = acc[i][j][r];
            }
        }
    } else {
        __syncthreads();
        unsigned short* Cs = sh;     // [128][128]
        #pragma unroll
        for (int i = 0; i < 4; ++i) {
            #pragma unroll
            for (int j = 0; j < 4; ++j) {
                int col = wn * 64 + j * 16 + lr;
                #pragma unroll
                for (int r = 0; r < 4; ++r)
                    Cs[(wm * 64 + i * 16 + lg * 4 + r) * 128 + col] = f2bf(acc[i][j][r]);
            }
        }
        __syncthreads();
        #pragma unroll
        for (int i = 0; i < 8; ++i) {
            int ch = i * 256 + t;
            int row = ch >> 4, c8 = (ch & 15) * 8;
            *(uint4*)&((unsigned short*)C)[(size_t)(m0 + row) * N + n0 + c8] =
                *(const uint4*)&Cs[row * 128 + c8];
        }
    }
}

// ------------------------------------------------------- RoPE + LayerNorm (q,k)
__global__ void k_ropeln(const unsigned short* __restrict__ proj,
                         const float* __restrict__ ln_scale,
                         const float* __restrict__ ln_bias,
                         unsigned short* __restrict__ Qh,
                         unsigned short* __restrict__ Kh) {
    const int n = blockIdx.x;
    const int wave = threadIdx.x >> 6, lane = threadIdx.x & 63;
    float inv = expf(-((float)(2 * lane) / 128.0f) * 9.210340371976184f);
    float ang = (float)n * inv;
    float c = cosf(ang), s = sinf(ang);
    const float sc1 = ln_scale[lane], sc2 = ln_scale[lane + 64];
    const float b1 = ln_bias[lane],  b2 = ln_bias[lane + 64];

    for (int r = wave; r < 32; r += 4) {
        int h = r >> 1, qk = r & 1;
        const unsigned short* src = proj + (size_t)n * (3 * EDIM) + qk * EDIM + h * HD;
        float x1 = bf2f(src[lane]), x2 = bf2f(src[lane + 64]);
        float o1 = x1 * c - x2 * s;
        float o2 = x1 * s + x2 * c;
        float sum = o1 + o2, sq = o1 * o1 + o2 * o2;
        #pragma unroll
        for (int d = 1; d < 64; d <<= 1) {
            sum += __shfl_xor(sum, d);
            sq  += __shfl_xor(sq, d);
        }
        float mean = sum * (1.0f / 128.0f);
        float var = sq * (1.0f / 128.0f) - mean * mean;
        float rstd = rsqrtf(var + 1e-5f);
        float y1 = (o1 - mean) * rstd * sc1 + b1;
        float y2 = (o2 - mean) * rstd * sc2 + b2;
        unsigned short* dst = (qk ? Kh : Qh) + ((size_t)h * N_SEQ + n) * HD;
        dst[lane]      = f2bf(y1);
        dst[lane + 64] = f2bf(y2);
    }
}

// ---------------------------------------------------- V transpose: [n][d] -> [d][n]
// Vt with the PV k-permutation baked into each 64-key tile:
// tile position p*8+i  <-  k = 32*(p>>2) + 16*(i>>2) + 4*(p&3) + (i&3)
__global__ void k_vtrans(const unsigned short* __restrict__ proj,
                         unsigned short* __restrict__ Vt) {
    __shared__ unsigned short Ls[64][136];
    const int h = blockIdx.y;
    const int n0 = blockIdx.x * 64;
    const int t = threadIdx.x;
    #pragma unroll
    for (int i = 0; i < 4; ++i) {
        int ch = i * 256 + t;
        int r = ch >> 4, d0 = (ch & 15) * 8;
        uint4 v = *(const uint4*)&proj[(size_t)(n0 + r) * (3 * EDIM) + 2 * EDIM + h * HD + d0];
        *(uint4*)&Ls[r][d0] = v;
    }
    __syncthreads();
    #pragma unroll
    for (int i = 0; i < 4; ++i) {
        int ch = i * 256 + t;
        int d = ch >> 3, p = ch & 7;
        unsigned short vals[8];
        #pragma unroll
        for (int j = 0; j < 8; ++j) {
            int ko = 32 * (p >> 2) + 16 * (j >> 2) + 4 * (p & 3) + (j & 3);
            vals[j] = Ls[ko][d];
        }
        uint4 pk;
        pk.x = (unsigned)vals[0] | ((unsigned)vals[1] << 16);
        pk.y = (unsigned)vals[2] | ((unsigned)vals[3] << 16);
        pk.z = (unsigned)vals[4] | ((unsigned)vals[5] << 16);
        pk.w = (unsigned)vals[6] | ((unsigned)vals[7] << 16);
        *(uint4*)&Vt[((size_t)h * HD + d) * N_SEQ + n0 + p * 8] = pk;
    }
}

// ------------------------------------------------------- polynomial attention
// v11: 128 q-rows/block, 4 waves = (wq 64-row half) x (wk 32-key half).
// Per wave: 64q x 32k per 64-key tile -> qf[4][4], acc[4][8]; LDS reads stay
// 16 b128/wave-tile for 2x the MFMA work of v10 (waves sharing wk read the
// SAME K/V fragments, so more q-rows/wave halves LDS reads per unit work —
// the measured bottleneck). In-register P (swapped QK^T + cvt_pk), permuted
// Vt single-b128 B-frags. wk-half combine via LDS in two 18-slot passes.
// 512 blocks, heavy+light pairing (66 units/CU), 2 blocks/CU.
__launch_bounds__(256, 2)
__global__ void k_attn(const unsigned short* __restrict__ Qh,
                       const unsigned short* __restrict__ Kh,
                       const unsigned short* __restrict__ Vt,
                       unsigned short* __restrict__ O) {
    // K[2][64][128] | V[2][128][64] = 64 KB; end reused as Xf(36KB)/Cs(32KB)
    __shared__ unsigned short pool[4 * 8192];

    const int t = threadIdx.x;
    const int w = t >> 6, lane = t & 63;
    const int wq = w >> 1, wk = w & 1;
    const int lg = lane >> 4, lr = lane & 15;

    // heavy/light pairing: batch 0 -> qt=31-qq (dispatched first), batch 1 -> qt=qq.
    const int s = blockIdx.x & 255;
    const int batch = blockIdx.x >> 8;
    const int h = (s & 7) * 2 + ((s >> 3) & 1);   // s%8 = XCD = h>>1
    const int qq = s >> 4;
    const int qt = batch ? qq : (31 - qq);
    const int q0 = qt * 128;
    const int qbase = q0 + wq * 64;   // this wave's first q-row
    const int kbase = wk * 32;        // this wave's k-offset within a tile

    // Q fragments (wave's 64 queries x 128 d)
    bf16x8 qf[4][4];
    #pragma unroll
    for (int mi = 0; mi < 4; ++mi)
        #pragma unroll
        for (int kk = 0; kk < 4; ++kk)
            qf[mi][kk] = *(const bf16x8*)&Qh[((size_t)h * N_SEQ + qbase + mi * 16 + lr) * HD + kk * 32 + lg * 8];

    f32x4 acc[4][8];
    #pragma unroll
    for (int i = 0; i < 4; ++i)
        #pragma unroll
        for (int j = 0; j < 8; ++j) acc[i][j] = f32x4{0.f, 0.f, 0.f, 0.f};
    f32x4 accd[4];
    #pragma unroll
    for (int i = 0; i < 4; ++i) accd[i] = f32x4{0.f, 0.f, 0.f, 0.f};

    // ones B-fragment: row-sum lands in output col 0 (k-permutation-invariant)
    bf16x8 onesf;
    {
        short ov = (lr == 0) ? (short)0x3F80 : (short)0;
        #pragma unroll
        for (int j = 0; j < 8; ++j) onesf[j] = ov;
    }

    // staging: per tile K 64x128 (1024 chunks, 4/thr) + V 128x64 (1024, 4/thr)
    int kch[4], vch[4];
    const unsigned short* kg[4];
    const unsigned short* vg[4];
    #pragma unroll
    for (int i = 0; i < 4; ++i) {
        int ch = i * 256 + t;
        kch[i] = ch;
        int r = ch >> 4, p = ch & 15;
        int csrc = (p & 8) | ((p ^ r) & 7);
        kg[i] = Kh + ((size_t)h * N_SEQ + r) * HD + csrc * 8;
    }
    #pragma unroll
    for (int i = 0; i < 4; ++i) {
        int ch = i * 256 + t;
        vch[i] = ch;
        int d = ch >> 3, p2 = ch & 7;
        int c2src = (p2 ^ d) & 7;
        vg[i] = Vt + ((size_t)h * HD + d) * N_SEQ + c2src * 8;
    }

    const int nkb = 2 * qt + 2;   // always even

    union U8 { unsigned u[4]; bf16x8 v; };

    auto stage = [&](unsigned short* Kn, unsigned short* Vn) {
        #pragma unroll
        for (int i = 0; i < 4; ++i) { gll16(kg[i], Kn + kch[i] * 8); kg[i] += 64 * HD; }
        #pragma unroll
        for (int i = 0; i < 4; ++i) { gll16(vg[i], Vn + vch[i] * 8); vg[i] += 64; }
    };

    auto compute = [&](int k0, const unsigned short* Kc, const unsigned short* Vc) {
        if (k0 + kbase > qbase + 63) return;   // wave's k-half fully masked
        // ---- S^T = K Q^T (swapped): lane holds S[k0+kbase+16nj+4lg+r][qbase+16mi+lr]
        f32x4 sa[4][2];
        #pragma unroll
        for (int i = 0; i < 4; ++i) {
            sa[i][0] = f32x4{0.f, 0.f, 0.f, 0.f};
            sa[i][1] = f32x4{0.f, 0.f, 0.f, 0.f};
        }
        #pragma unroll
        for (int nj = 0; nj < 2; ++nj) {
            bf16x8 kf4[4];
            #pragma unroll
            for (int kk = 0; kk < 4; ++kk) {
                int row = kbase + nj * 16 + lr;
                int c = kk * 4 + lg;
                int cs = (c & 8) | ((c ^ row) & 7);
                kf4[kk] = *(const bf16x8*)&Kc[row * 128 + cs * 8];
            }
            __builtin_amdgcn_s_setprio(1);
            #pragma unroll
            for (int kk = 0; kk < 4; ++kk)
                #pragma unroll
                for (int mi = 0; mi < 4; ++mi)
                    sa[mi][nj] = __builtin_amdgcn_mfma_f32_16x16x32_bf16(
                        kf4[kk], qf[mi][kk], sa[mi][nj], 0, 0, 0);
            __builtin_amdgcn_s_setprio(0);
        }

        // ---- mask + ^4 + pack to bf16 pairs in registers
        unsigned wreg[4][2][2];
        const bool nomask = (k0 + kbase + 31 <= qbase);
        #pragma unroll
        for (int mi = 0; mi < 4; ++mi)
            #pragma unroll
            for (int nj = 0; nj < 2; ++nj) {
                float p[4];
                #pragma unroll
                for (int r = 0; r < 4; ++r) {
                    float sv = sa[mi][nj][r];
                    float t2 = sv * sv;
                    p[r] = t2 * t2;
                    if (!nomask) {
                        int gk = k0 + kbase + nj * 16 + lg * 4 + r;
                        int gq = qbase + mi * 16 + lr;
                        p[r] = (gk <= gq) ? p[r] : 0.0f;
                    }
                }
                asm("v_cvt_pk_bf16_f32 %0, %1, %2" : "=v"(wreg[mi][nj][0]) : "v"(p[0]), "v"(p[1]));
                asm("v_cvt_pk_bf16_f32 %0, %1, %2" : "=v"(wreg[mi][nj][1]) : "v"(p[2]), "v"(p[3]));
            }

        // ---- O += P V (k-half), denom += P * ones
        bf16x8 pa[4];
        #pragma unroll
        for (int mi = 0; mi < 4; ++mi) {
            U8 u;
            u.u[0] = wreg[mi][0][0];
            u.u[1] = wreg[mi][0][1];
            u.u[2] = wreg[mi][1][0];
            u.u[3] = wreg[mi][1][1];
            pa[mi] = u.v;
        }
        __builtin_amdgcn_s_setprio(1);
        #pragma unroll
        for (int ni = 0; ni < 8; ++ni) {
            int d = ni * 16 + lr;
            int cs = ((wk * 4 + lg) ^ (d & 7)) & 7;
            bf16x8 vf = *(const bf16x8*)&Vc[d * 64 + cs * 8];
            #pragma unroll
            for (int mi = 0; mi < 4; ++mi)
                acc[mi][ni] = __builtin_amdgcn_mfma_f32_16x16x32_bf16(pa[mi], vf, acc[mi][ni], 0, 0, 0);
        }
        #pragma unroll
        for (int mi = 0; mi < 4; ++mi)
            accd[mi] = __builtin_amdgcn_mfma_f32_16x16x32_bf16(pa[mi], onesf, accd[mi], 0, 0, 0);
        __builtin_amdgcn_s_setprio(0);
    };

    // prologue: stage tile 0 into buf 0
    stage(pool, pool + 16384);

    for (int kb = 0; kb < nkb; kb += 2) {
        stage(pool + 8192, pool + 16384 + 8192);  // tile kb+1 -> buf1
        asm volatile("s_waitcnt vmcnt(8)" ::: "memory");
        __builtin_amdgcn_s_barrier();
        compute(kb * 64, pool, pool + 16384);
        __builtin_amdgcn_s_barrier();
        if (kb + 2 < nkb) {
            stage(pool, pool + 16384);            // tile kb+2 -> buf0
            asm volatile("s_waitcnt vmcnt(8)" ::: "memory");
        } else {
            asm volatile("s_waitcnt vmcnt(0)" ::: "memory");
        }
        __builtin_amdgcn_s_barrier();
        compute((kb + 1) * 64, pool + 8192, pool + 16384 + 8192);
        __builtin_amdgcn_s_barrier();
    }

    // ---- combine wk halves: two 18-slot f32 passes through LDS ----
    asm volatile("s_waitcnt vmcnt(0)" ::: "memory");
    float* Xf = (float*)pool;                 // [wq][18 slots][64 lanes][4] f32
    const int xbase = wq * 4608 + lane * 4;
    #pragma unroll
    for (int p = 0; p < 2; ++p) {
        __syncthreads();
        if (wk == 1) {
            #pragma unroll
            for (int i = 0; i < 2; ++i) {
                #pragma unroll
                for (int ni = 0; ni < 8; ++ni)
                    *(f32x4*)&Xf[xbase + (i * 8 + ni) * 256] = acc[p * 2 + i][ni];
                *(f32x4*)&Xf[xbase + (16 + i) * 256] = accd[p * 2 + i];
            }
        }
        __syncthreads();
        if (wk == 0) {
            #pragma unroll
            for (int i = 0; i < 2; ++i) {
                #pragma unroll
                for (int ni = 0; ni < 8; ++ni) {
                    f32x4 o = *(const f32x4*)&Xf[xbase + (i * 8 + ni) * 256];
                    acc[p * 2 + i][ni][0] += o[0]; acc[p * 2 + i][ni][1] += o[1];
                    acc[p * 2 + i][ni][2] += o[2]; acc[p * 2 + i][ni][3] += o[3];
                }
                f32x4 od = *(const f32x4*)&Xf[xbase + (16 + i) * 256];
                accd[p * 2 + i][0] += od[0]; accd[p * 2 + i][1] += od[1];
                accd[p * 2 + i][2] += od[2]; accd[p * 2 + i][3] += od[3];
            }
        }
    }
    __syncthreads();
    unsigned short* Cs = pool;                // [128][128] bf16 = 32 KB
    if (wk == 0) {
        #pragma unroll
        for (int mi = 0; mi < 4; ++mi) {
            #pragma unroll
            for (int r = 0; r < 4; ++r) {
                float dv = __shfl(accd[mi][r], lane & 48);  // col 0 in lane lg*16
                float rinv = 1.0f / dv;
                int rw = wq * 64 + mi * 16 + lg * 4 + r;
                #pragma unroll
                for (int ni = 0; ni < 8; ++ni)
                    Cs[rw * 128 + ni * 16 + lr] = f2bf(acc[mi][ni][r] * rinv);
            }
        }
    }
    __syncthreads();
    #pragma unroll
    for (int i = 0; i < 8; ++i) {
        int ch = i * 256 + t;                 // 2048 chunks of 8 shorts
        int row = ch >> 4, c8 = (ch & 15) * 8;
        *(uint4*)&O[(size_t)(q0 + row) * EDIM + h * HD + c8] = *(const uint4*)&Cs[row * 128 + c8];
    }
}

// ---------------------------------------------------------------- launch
extern "C" void kernel_launch(void* const* d_in, const int* in_sizes, int n_in,
                              void* d_out, int out_size, void* d_ws, size_t ws_size,
                              hipStream_t stream) {
    const float* x        = (const float*)d_in[0];
    const float* w_qkv    = (const float*)d_in[1];
    const float* w_out    = (const float*)d_in[2];
    const float* ln_scale = (const float*)d_in[3];
    const float* ln_bias  = (const float*)d_in[4];

    if (ws_size < 134217728u) return;  // need 128 MiB

    char* ws = (char*)d_ws;
    unsigned short* xb    = (unsigned short*)(ws);              // 16 MiB; reused as attnO
    unsigned short* wqkvT = (unsigned short*)(ws + 16777216);   // 24 MiB; reused as Qh
    unsigned short* woutT = (unsigned short*)(ws + 41943040);   //  8 MiB
    unsigned short* proj  = (unsigned short*)(ws + 50331648);   // 48 MiB
    unsigned short* Kh    = (unsigned short*)(ws + 100663296);  // 16 MiB
    unsigned short* Vt    = (unsigned short*)(ws + 117440512);  // 16 MiB
    unsigned short* Qh    = wqkvT;   // alias: w_qkvT dead after GEMM1
    unsigned short* attnO = xb;      // alias: xb dead after GEMM1

    k_convert_x<<<2048, 256, 0, stream>>>(x, xb, (N_SEQ * EDIM) / 4);
    k_transpose_f32_bf16<<<dim3(3 * EDIM / 64, EDIM / 64), 256, 0, stream>>>(w_qkv, wqkvT, EDIM, 3 * EDIM);
    k_transpose_f32_bf16<<<dim3(EDIM / 64, EDIM / 64), 256, 0, stream>>>(w_out, woutT, EDIM, EDIM);
    k_gemm_bt<0><<<dim3(3 * EDIM / 128, N_SEQ / 128), 256, 0, stream>>>(xb, wqkvT, proj, N_SEQ, 3 * EDIM, EDIM);
    k_ropeln<<<N_SEQ, 256, 0, stream>>>(proj, ln_scale, ln_bias, Qh, Kh);
    k_vtrans<<<dim3(N_SEQ / 64, NH), 256, 0, stream>>>(proj, Vt);
    k_attn<<<512, 256, 0, stream>>>(Qh, Kh, Vt, attnO);
    k_gemm_bt<1><<<dim3(EDIM / 128, N_SEQ / 128), 256, 0, stream>>>(attnO, woutT, (float*)d_out, N_SEQ, EDIM, EDIM);
}

// Round 14
// 310.159 us; speedup vs baseline: 1.7350x; 1.7350x over previous
//
#include <hip/hip_runtime.h>
#include <stdint.h>
#include <math.h>

// Problem constants
#define N_SEQ 4096
#define EDIM  2048
#define NH    16
#define HD    128

typedef __attribute__((ext_vector_type(8))) short bf16x8;
typedef __attribute__((ext_vector_type(4))) float f32x4;

#define AS1 __attribute__((address_space(1)))
#define AS3 __attribute__((address_space(3)))

__device__ __forceinline__ void gll16(const unsigned short* g, unsigned short* l) {
    __builtin_amdgcn_global_load_lds((const AS1 unsigned int*)g,
                                     (AS3 unsigned int*)l, 16, 0, 0);
}

__device__ __forceinline__ unsigned short f2bf(float f) {
    union { float f; unsigned u; } v; v.f = f;
    unsigned r = v.u + 0x7FFFu + ((v.u >> 16) & 1u);
    return (unsigned short)(r >> 16);
}
__device__ __forceinline__ float bf2f(unsigned short h) {
    union { unsigned u; float f; } v; v.u = ((unsigned)h) << 16;
    return v.f;
}

// ---------------------------------------------------------------- convert x
__global__ void k_convert_x(const float* __restrict__ x,
                            unsigned short* __restrict__ xb, int n4) {
    int i = blockIdx.x * blockDim.x + threadIdx.x;
    int stride = gridDim.x * blockDim.x;
    for (; i < n4; i += stride) {
        float4 v = ((const float4*)x)[i];
        ushort4 o;
        o.x = f2bf(v.x); o.y = f2bf(v.y); o.z = f2bf(v.z); o.w = f2bf(v.w);
        ((ushort4*)xb)[i] = o;
    }
}

// ---------------------------------------------- transpose f32 (RxC) -> bf16 (CxR)
__global__ void k_transpose_f32_bf16(const float* __restrict__ in,
                                     unsigned short* __restrict__ out,
                                     int R, int C) {
    __shared__ unsigned short Ls[64][68];
    const int c0 = blockIdx.x * 64, r0 = blockIdx.y * 64;
    const int t = threadIdx.x;
    #pragma unroll
    for (int i = 0; i < 4; ++i) {
        int ch = i * 256 + t;              // 1024 float4 chunks
        int r = ch >> 4, c4 = (ch & 15) * 4;
        float4 v = *(const float4*)&in[(size_t)(r0 + r) * C + c0 + c4];
        ushort4 o;
        o.x = f2bf(v.x); o.y = f2bf(v.y); o.z = f2bf(v.z); o.w = f2bf(v.w);
        *(ushort4*)&Ls[r][c4] = o;
    }
    __syncthreads();
    #pragma unroll
    for (int i = 0; i < 2; ++i) {
        int ch = i * 256 + t;              // 512 chunks of 8 bf16
        int rr = ch >> 3, c8 = (ch & 7) * 8;
        unsigned short vals[8];
        #pragma unroll
        for (int j = 0; j < 8; ++j) vals[j] = Ls[c8 + j][rr];
        uint4 pk;
        pk.x = (unsigned)vals[0] | ((unsigned)vals[1] << 16);
        pk.y = (unsigned)vals[2] | ((unsigned)vals[3] << 16);
        pk.z = (unsigned)vals[4] | ((unsigned)vals[5] << 16);
        pk.w = (unsigned)vals[6] | ((unsigned)vals[7] << 16);
        *(uint4*)&out[(size_t)(c0 + rr) * R + r0 + c8] = pk;
    }
}

// ---------------------------------------------------------------- bt GEMM (m97)
// C[M,N] = A[M,K] * Bt[N,K]^T  (bf16 in, f32 acc, bf16 or f32 out)
template<int F32OUT>
__launch_bounds__(256, 2)
__global__ void k_gemm_bt(const unsigned short* __restrict__ A,
                          const unsigned short* __restrict__ Bt,
                          void* __restrict__ C,
                          int M, int N, int K) {
    __shared__ unsigned short sh[2 * 128 * 64];   // As | Bs, linear [128][64]
    unsigned short* As = sh;
    unsigned short* Bs = sh + 128 * 64;

    const int t = threadIdx.x;
    const int wave = t >> 6, lane = t & 63;
    const int wm = wave >> 1, wn = wave & 1;
    const int lg = lane >> 4, lr = lane & 15;

    const int nbx = gridDim.x;
    const int nwg = nbx * gridDim.y;
    int bid = blockIdx.y * nbx + blockIdx.x;
    int swz = (bid & 7) * (nwg >> 3) + (bid >> 3);
    const int m0 = (swz / nbx) * 128;
    const int n0 = (swz % nbx) * 128;

    const unsigned short* aptr = A  + (size_t)m0 * K;
    const unsigned short* bptr = Bt + (size_t)n0 * K;

    f32x4 acc[4][4];
    #pragma unroll
    for (int i = 0; i < 4; ++i)
        #pragma unroll
        for (int j = 0; j < 4; ++j) acc[i][j] = f32x4{0.f, 0.f, 0.f, 0.f};

    int schr[4], srow[4], scb[4];
    #pragma unroll
    for (int i = 0; i < 4; ++i) {
        int ch = (i * 4 + wave) * 64 + lane;
        schr[i] = ch;
        srow[i] = ch >> 3;
        scb[i]  = (ch & 7) ^ ((ch >> 3) & 7);
    }

    const int nkb = K >> 6;
    for (int kb = 0; kb < nkb; ++kb) {
        __syncthreads();
        #pragma unroll
        for (int i = 0; i < 4; ++i) {
            const size_t goff = (size_t)srow[i] * K + (size_t)kb * 64 + scb[i] * 8;
            gll16(&aptr[goff], &As[schr[i] * 8]);
            gll16(&bptr[goff], &Bs[schr[i] * 8]);
        }
        __syncthreads();

        #pragma unroll
        for (int kk = 0; kk < 2; ++kk) {
            bf16x8 af[4], bf[4];
            const int cbx = ((kk * 4 + lg) ^ (lr & 7)) * 8;
            #pragma unroll
            for (int i = 0; i < 4; ++i) {
                af[i] = *(const bf16x8*)&As[(wm * 64 + i * 16 + lr) * 64 + cbx];
                bf[i] = *(const bf16x8*)&Bs[(wn * 64 + i * 16 + lr) * 64 + cbx];
            }
            #pragma unroll
            for (int i = 0; i < 4; ++i)
                #pragma unroll
                for (int j = 0; j < 4; ++j)
                    acc[i][j] = __builtin_amdgcn_mfma_f32_16x16x32_bf16(af[i], bf[j], acc[i][j], 0, 0, 0);
        }
    }

    if (F32OUT) {
        #pragma unroll
        for (int i = 0; i < 4; ++i) {
            int row0 = m0 + wm * 64 + i * 16 + lg * 4;
            #pragma unroll
            for (int j = 0; j < 4; ++j) {
                int col = n0 + wn * 64 + j * 16 + lr;
                #pragma unroll
                for (int r = 0; r < 4; ++r)
                    ((float*)C)[(size_t)(row0 + r) * N + col] = acc[i][j][r];
            }
        }
    } else {
        __syncthreads();
        unsigned short* Cs = sh;     // [128][128]
        #pragma unroll
        for (int i = 0; i < 4; ++i) {
            #pragma unroll
            for (int j = 0; j < 4; ++j) {
                int col = wn * 64 + j * 16 + lr;
                #pragma unroll
                for (int r = 0; r < 4; ++r)
                    Cs[(wm * 64 + i * 16 + lg * 4 + r) * 128 + col] = f2bf(acc[i][j][r]);
            }
        }
        __syncthreads();
        #pragma unroll
        for (int i = 0; i < 8; ++i) {
            int ch = i * 256 + t;
            int row = ch >> 4, c8 = (ch & 15) * 8;
            *(uint4*)&((unsigned short*)C)[(size_t)(m0 + row) * N + n0 + c8] =
                *(const uint4*)&Cs[row * 128 + c8];
        }
    }
}

// ------------------------------------------------------- RoPE + LayerNorm (q,k)
__global__ void k_ropeln(const unsigned short* __restrict__ proj,
                         const float* __restrict__ ln_scale,
                         const float* __restrict__ ln_bias,
                         unsigned short* __restrict__ Qh,
                         unsigned short* __restrict__ Kh) {
    const int n = blockIdx.x;
    const int wave = threadIdx.x >> 6, lane = threadIdx.x & 63;
    float inv = expf(-((float)(2 * lane) / 128.0f) * 9.210340371976184f);
    float ang = (float)n * inv;
    float c = cosf(ang), s = sinf(ang);
    const float sc1 = ln_scale[lane], sc2 = ln_scale[lane + 64];
    const float b1 = ln_bias[lane],  b2 = ln_bias[lane + 64];

    for (int r = wave; r < 32; r += 4) {
        int h = r >> 1, qk = r & 1;
        const unsigned short* src = proj + (size_t)n * (3 * EDIM) + qk * EDIM + h * HD;
        float x1 = bf2f(src[lane]), x2 = bf2f(src[lane + 64]);
        float o1 = x1 * c - x2 * s;
        float o2 = x1 * s + x2 * c;
        float sum = o1 + o2, sq = o1 * o1 + o2 * o2;
        #pragma unroll
        for (int d = 1; d < 64; d <<= 1) {
            sum += __shfl_xor(sum, d);
            sq  += __shfl_xor(sq, d);
        }
        float mean = sum * (1.0f / 128.0f);
        float var = sq * (1.0f / 128.0f) - mean * mean;
        float rstd = rsqrtf(var + 1e-5f);
        float y1 = (o1 - mean) * rstd * sc1 + b1;
        float y2 = (o2 - mean) * rstd * sc2 + b2;
        unsigned short* dst = (qk ? Kh : Qh) + ((size_t)h * N_SEQ + n) * HD;
        dst[lane]      = f2bf(y1);
        dst[lane + 64] = f2bf(y2);
    }
}

// ---------------------------------------------------- V transpose: [n][d] -> [d][n]
// Vt with the PV k-permutation baked into each 64-key tile:
// tile position p*8+i  <-  k = 32*(p>>2) + 16*(i>>2) + 4*(p&3) + (i&3)
__global__ void k_vtrans(const unsigned short* __restrict__ proj,
                         unsigned short* __restrict__ Vt) {
    __shared__ unsigned short Ls[64][136];
    const int h = blockIdx.y;
    const int n0 = blockIdx.x * 64;
    const int t = threadIdx.x;
    #pragma unroll
    for (int i = 0; i < 4; ++i) {
        int ch = i * 256 + t;
        int r = ch >> 4, d0 = (ch & 15) * 8;
        uint4 v = *(const uint4*)&proj[(size_t)(n0 + r) * (3 * EDIM) + 2 * EDIM + h * HD + d0];
        *(uint4*)&Ls[r][d0] = v;
    }
    __syncthreads();
    #pragma unroll
    for (int i = 0; i < 4; ++i) {
        int ch = i * 256 + t;
        int d = ch >> 3, p = ch & 7;
        unsigned short vals[8];
        #pragma unroll
        for (int j = 0; j < 8; ++j) {
            int ko = 32 * (p >> 2) + 16 * (j >> 2) + 4 * (p & 3) + (j & 3);
            vals[j] = Ls[ko][d];
        }
        uint4 pk;
        pk.x = (unsigned)vals[0] | ((unsigned)vals[1] << 16);
        pk.y = (unsigned)vals[2] | ((unsigned)vals[3] << 16);
        pk.z = (unsigned)vals[4] | ((unsigned)vals[5] << 16);
        pk.w = (unsigned)vals[6] | ((unsigned)vals[7] << 16);
        *(uint4*)&Vt[((size_t)h * HD + d) * N_SEQ + n0 + p * 8] = pk;
    }
}

// ------------------------------------------------------- polynomial attention
// v12 = v10 core (64 q-rows/block, 4 waves = wq x wk k-split, in-register P,
// permuted-Vt b128 B-frags, unroll-2 dbuf, vmcnt(8)) with BALANCED DISPATCH:
// per-XCD alternating complementary pairs. Block decode keeps b%8 = XCD =
// h>>1 (K/V L2 affinity); within an XCD the qt sequence is 63,0,62,1,...
// so heavy (nkb=64-r) and light (nkb=r+1) interleave -> greedy slot refill
// packs each CU to ~65 iter-units (vs 96 for all-heavy-then-all-light LPT).
__launch_bounds__(256, 2)
__global__ void k_attn(const unsigned short* __restrict__ Qh,
                       const unsigned short* __restrict__ Kh,
                       const unsigned short* __restrict__ Vt,
                       unsigned short* __restrict__ O) {
    // K[2][64][128] | V[2][128][64] = 64 KB; end reused as Xf(36KB)+Cs(16KB)
    __shared__ unsigned short pool[4 * 8192];

    const int t = threadIdx.x;
    const int w = t >> 6, lane = t & 63;
    const int wq = w >> 1, wk = w & 1;
    const int lg = lane >> 4, lr = lane & 15;

    // balanced interleaved dispatch (see header comment)
    const int b = blockIdx.x;
    const int xcd = b & 7;
    const int j = b >> 3;                  // 0..127 within XCD
    const int h = xcd * 2 + (j >> 6);      // 2 heads per XCD
    const int jj = j & 63;
    const int qt = (jj & 1) ? (jj >> 1) : (63 - (jj >> 1));
    const int q0 = qt * 64;
    const int qbase = q0 + wq * 32;   // this wave's first q-row
    const int kbase = wk * 32;        // this wave's k-offset within a tile

    // Q fragments (wave's 32 queries x 128 d)
    bf16x8 qf[2][4];
    #pragma unroll
    for (int mi = 0; mi < 2; ++mi)
        #pragma unroll
        for (int kk = 0; kk < 4; ++kk)
            qf[mi][kk] = *(const bf16x8*)&Qh[((size_t)h * N_SEQ + qbase + mi * 16 + lr) * HD + kk * 32 + lg * 8];

    f32x4 acc[2][8];
    #pragma unroll
    for (int i = 0; i < 2; ++i)
        #pragma unroll
        for (int j2 = 0; j2 < 8; ++j2) acc[i][j2] = f32x4{0.f, 0.f, 0.f, 0.f};
    f32x4 accd[2];
    accd[0] = f32x4{0.f, 0.f, 0.f, 0.f};
    accd[1] = f32x4{0.f, 0.f, 0.f, 0.f};

    // ones B-fragment: row-sum lands in output col 0 (k-permutation-invariant)
    bf16x8 onesf;
    {
        short ov = (lr == 0) ? (short)0x3F80 : (short)0;
        #pragma unroll
        for (int j2 = 0; j2 < 8; ++j2) onesf[j2] = ov;
    }

    // staging: per tile K 64x128 (1024 chunks, 4/thr) + V 128x64 (1024, 4/thr)
    int kch[4], vch[4];
    const unsigned short* kg[4];
    const unsigned short* vg[4];
    #pragma unroll
    for (int i = 0; i < 4; ++i) {
        int ch = i * 256 + t;
        kch[i] = ch;
        int r = ch >> 4, p = ch & 15;
        int csrc = (p & 8) | ((p ^ r) & 7);
        kg[i] = Kh + ((size_t)h * N_SEQ + r) * HD + csrc * 8;
    }
    #pragma unroll
    for (int i = 0; i < 4; ++i) {
        int ch = i * 256 + t;
        vch[i] = ch;
        int d = ch >> 3, p2 = ch & 7;
        int c2src = (p2 ^ d) & 7;
        vg[i] = Vt + ((size_t)h * HD + d) * N_SEQ + c2src * 8;
    }

    const int nkb = qt + 1;

    union U8 { unsigned u[4]; bf16x8 v; };

    auto stage = [&](unsigned short* Kn, unsigned short* Vn) {
        #pragma unroll
        for (int i = 0; i < 4; ++i) { gll16(kg[i], Kn + kch[i] * 8); kg[i] += 64 * HD; }
        #pragma unroll
        for (int i = 0; i < 4; ++i) { gll16(vg[i], Vn + vch[i] * 8); vg[i] += 64; }
    };

    auto compute = [&](int k0, const unsigned short* Kc, const unsigned short* Vc) {
        if (k0 + kbase > qbase + 31) return;   // wave's k-half fully masked
        // ---- S^T = K Q^T (swapped): lane holds S[k0+kbase+16nj+4lg+r][qbase+16mi+lr]
        f32x4 sa[2][2];
        #pragma unroll
        for (int i = 0; i < 2; ++i) {
            sa[i][0] = f32x4{0.f, 0.f, 0.f, 0.f};
            sa[i][1] = f32x4{0.f, 0.f, 0.f, 0.f};
        }
        bf16x8 kf[2][4];
        #pragma unroll
        for (int nj = 0; nj < 2; ++nj)
            #pragma unroll
            for (int kk = 0; kk < 4; ++kk) {
                int row = kbase + nj * 16 + lr;
                int c = kk * 4 + lg;
                int cs = (c & 8) | ((c ^ row) & 7);
                kf[nj][kk] = *(const bf16x8*)&Kc[row * 128 + cs * 8];
            }
        __builtin_amdgcn_s_setprio(1);
        #pragma unroll
        for (int kk = 0; kk < 4; ++kk)
            #pragma unroll
            for (int nj = 0; nj < 2; ++nj)
                #pragma unroll
                for (int mi = 0; mi < 2; ++mi)
                    sa[mi][nj] = __builtin_amdgcn_mfma_f32_16x16x32_bf16(
                        kf[nj][kk], qf[mi][kk], sa[mi][nj], 0, 0, 0);
        __builtin_amdgcn_s_setprio(0);

        // ---- mask + ^4 + pack to bf16 pairs in registers
        unsigned wreg[2][2][2];
        const bool nomask = (k0 + kbase + 31 <= qbase);
        #pragma unroll
        for (int mi = 0; mi < 2; ++mi)
            #pragma unroll
            for (int nj = 0; nj < 2; ++nj) {
                float p[4];
                #pragma unroll
                for (int r = 0; r < 4; ++r) {
                    float sv = sa[mi][nj][r];
                    float t2 = sv * sv;
                    p[r] = t2 * t2;
                    if (!nomask) {
                        int gk = k0 + kbase + nj * 16 + lg * 4 + r;
                        int gq = qbase + mi * 16 + lr;
                        p[r] = (gk <= gq) ? p[r] : 0.0f;
                    }
                }
                asm("v_cvt_pk_bf16_f32 %0, %1, %2" : "=v"(wreg[mi][nj][0]) : "v"(p[0]), "v"(p[1]));
                asm("v_cvt_pk_bf16_f32 %0, %1, %2" : "=v"(wreg[mi][nj][1]) : "v"(p[2]), "v"(p[3]));
            }

        // ---- O += P V (k-half), denom += P * ones
        bf16x8 pa[2];
        #pragma unroll
        for (int mi = 0; mi < 2; ++mi) {
            U8 u;
            u.u[0] = wreg[mi][0][0];
            u.u[1] = wreg[mi][0][1];
            u.u[2] = wreg[mi][1][0];
            u.u[3] = wreg[mi][1][1];
            pa[mi] = u.v;
        }
        __builtin_amdgcn_s_setprio(1);
        #pragma unroll
        for (int ni = 0; ni < 8; ++ni) {
            int d = ni * 16 + lr;
            int cs = ((wk * 4 + lg) ^ (d & 7)) & 7;
            bf16x8 vf = *(const bf16x8*)&Vc[d * 64 + cs * 8];
            #pragma unroll
            for (int mi = 0; mi < 2; ++mi)
                acc[mi][ni] = __builtin_amdgcn_mfma_f32_16x16x32_bf16(pa[mi], vf, acc[mi][ni], 0, 0, 0);
        }
        #pragma unroll
        for (int mi = 0; mi < 2; ++mi)
            accd[mi] = __builtin_amdgcn_mfma_f32_16x16x32_bf16(pa[mi], onesf, accd[mi], 0, 0, 0);
        __builtin_amdgcn_s_setprio(0);
    };

    // prologue: stage tile 0 into buf 0
    stage(pool, pool + 16384);
    int kb0 = 0;
    if (nkb & 1) {
        asm volatile("s_waitcnt vmcnt(0)" ::: "memory");
        __builtin_amdgcn_s_barrier();
        compute(0, pool, pool + 16384);
        __builtin_amdgcn_s_barrier();
        if (nkb > 1) stage(pool, pool + 16384);   // tile 1 -> buf0
        kb0 = 1;
    }
    for (int kb = kb0; kb < nkb; kb += 2) {
        stage(pool + 8192, pool + 16384 + 8192);  // tile kb+1 -> buf1
        asm volatile("s_waitcnt vmcnt(8)" ::: "memory");
        __builtin_amdgcn_s_barrier();
        compute(kb * 64, pool, pool + 16384);
        __builtin_amdgcn_s_barrier();
        if (kb + 2 < nkb) {
            stage(pool, pool + 16384);            // tile kb+2 -> buf0
            asm volatile("s_waitcnt vmcnt(8)" ::: "memory");
        } else {
            asm volatile("s_waitcnt vmcnt(0)" ::: "memory");
        }
        __builtin_amdgcn_s_barrier();
        compute((kb + 1) * 64, pool + 8192, pool + 16384 + 8192);
        __builtin_amdgcn_s_barrier();
    }

    // ---- combine wk halves (f32 add via LDS, slot-major conflict-free) ----
    asm volatile("s_waitcnt vmcnt(0)" ::: "memory");   // drain stray prefetches
    __syncthreads();
    float* Xf = (float*)pool;                 // [wq][18 slots][64 lanes][4] f32
    const int xbase = wq * 4608 + lane * 4;
    if (wk == 1) {
        #pragma unroll
        for (int mi = 0; mi < 2; ++mi) {
            #pragma unroll
            for (int ni = 0; ni < 8; ++ni)
                *(f32x4*)&Xf[xbase + (mi * 8 + ni) * 256] = acc[mi][ni];
            *(f32x4*)&Xf[xbase + (16 + mi) * 256] = accd[mi];
        }
    }
    __syncthreads();
    unsigned short* Cs = pool + 20480;        // [64][128] bf16, disjoint from Xf
    if (wk == 0) {
        #pragma unroll
        for (int mi = 0; mi < 2; ++mi) {
            #pragma unroll
            for (int ni = 0; ni < 8; ++ni) {
                f32x4 o = *(const f32x4*)&Xf[xbase + (mi * 8 + ni) * 256];
                acc[mi][ni][0] += o[0]; acc[mi][ni][1] += o[1];
                acc[mi][ni][2] += o[2]; acc[mi][ni][3] += o[3];
            }
            f32x4 od = *(const f32x4*)&Xf[xbase + (16 + mi) * 256];
            accd[mi][0] += od[0]; accd[mi][1] += od[1];
            accd[mi][2] += od[2]; accd[mi][3] += od[3];
        }
        // divide + stage bf16 tile
        #pragma unroll
        for (int mi = 0; mi < 2; ++mi) {
            #pragma unroll
            for (int r = 0; r < 4; ++r) {
                float dv = __shfl(accd[mi][r], lane & 48);  // col 0 in lane lg*16
                float rinv = 1.0f / dv;
                int rw = wq * 32 + mi * 16 + lg * 4 + r;
                #pragma unroll
                for (int ni = 0; ni < 8; ++ni)
                    Cs[rw * 128 + ni * 16 + lr] = f2bf(acc[mi][ni][r] * rinv);
            }
        }
    }
    __syncthreads();
    #pragma unroll
    for (int i = 0; i < 4; ++i) {
        int ch = i * 256 + t;                 // 1024 chunks of 8 shorts
        int row = ch >> 4, c8 = (ch & 15) * 8;
        *(uint4*)&O[(size_t)(q0 + row) * EDIM + h * HD + c8] = *(const uint4*)&Cs[row * 128 + c8];
    }
}

// ---------------------------------------------------------------- launch
extern "C" void kernel_launch(void* const* d_in, const int* in_sizes, int n_in,
                              void* d_out, int out_size, void* d_ws, size_t ws_size,
                              hipStream_t stream) {
    const float* x        = (const float*)d_in[0];
    const float* w_qkv    = (const float*)d_in[1];
    const float* w_out    = (const float*)d_in[2];
    const float* ln_scale = (const float*)d_in[3];
    const float* ln_bias  = (const float*)d_in[4];

    if (ws_size < 134217728u) return;  // need 128 MiB

    char* ws = (char*)d_ws;
    unsigned short* xb    = (unsigned short*)(ws);              // 16 MiB; reused as attnO
    unsigned short* wqkvT = (unsigned short*)(ws + 16777216);   // 24 MiB; reused as Qh
    unsigned short* woutT = (unsigned short*)(ws + 41943040);   //  8 MiB
    unsigned short* proj  = (unsigned short*)(ws + 50331648);   // 48 MiB
    unsigned short* Kh    = (unsigned short*)(ws + 100663296);  // 16 MiB
    unsigned short* Vt    = (unsigned short*)(ws + 117440512);  // 16 MiB
    unsigned short* Qh    = wqkvT;   // alias: w_qkvT dead after GEMM1
    unsigned short* attnO = xb;      // alias: xb dead after GEMM1

    k_convert_x<<<2048, 256, 0, stream>>>(x, xb, (N_SEQ * EDIM) / 4);
    k_transpose_f32_bf16<<<dim3(3 * EDIM / 64, EDIM / 64), 256, 0, stream>>>(w_qkv, wqkvT, EDIM, 3 * EDIM);
    k_transpose_f32_bf16<<<dim3(EDIM / 64, EDIM / 64), 256, 0, stream>>>(w_out, woutT, EDIM, EDIM);
    k_gemm_bt<0><<<dim3(3 * EDIM / 128, N_SEQ / 128), 256, 0, stream>>>(xb, wqkvT, proj, N_SEQ, 3 * EDIM, EDIM);
    k_ropeln<<<N_SEQ, 256, 0, stream>>>(proj, ln_scale, ln_bias, Qh, Kh);
    k_vtrans<<<dim3(N_SEQ / 64, NH), 256, 0, stream>>>(proj, Vt);
    k_attn<<<1024, 256, 0, stream>>>(Qh, Kh, Vt, attnO);
    k_gemm_bt<1><<<dim3(EDIM / 128, N_SEQ / 128), 256, 0, stream>>>(attnO, woutT, (float*)d_out, N_SEQ, EDIM, EDIM);
}

// Round 15
// 268.965 us; speedup vs baseline: 2.0007x; 1.1532x over previous
//
#include <hip/hip_runtime.h>
#include <stdint.h>
#include <math.h>

// Problem constants
#define N_SEQ 4096
#define EDIM  2048
#define NH    16
#define HD    128

typedef __attribute__((ext_vector_type(8))) short bf16x8;
typedef __attribute__((ext_vector_type(4))) float f32x4;

#define AS1 __attribute__((address_space(1)))
#define AS3 __attribute__((address_space(3)))

__device__ __forceinline__ void gll16(const unsigned short* g, unsigned short* l) {
    __builtin_amdgcn_global_load_lds((const AS1 unsigned int*)g,
                                     (AS3 unsigned int*)l, 16, 0, 0);
}

__device__ __forceinline__ unsigned short f2bf(float f) {
    union { float f; unsigned u; } v; v.f = f;
    unsigned r = v.u + 0x7FFFu + ((v.u >> 16) & 1u);
    return (unsigned short)(r >> 16);
}
__device__ __forceinline__ float bf2f(unsigned short h) {
    union { unsigned u; float f; } v; v.u = ((unsigned)h) << 16;
    return v.f;
}

// ---------------------------------------------------------------- convert x
__global__ void k_convert_x(const float* __restrict__ x,
                            unsigned short* __restrict__ xb, int n4) {
    int i = blockIdx.x * blockDim.x + threadIdx.x;
    int stride = gridDim.x * blockDim.x;
    for (; i < n4; i += stride) {
        float4 v = ((const float4*)x)[i];
        ushort4 o;
        o.x = f2bf(v.x); o.y = f2bf(v.y); o.z = f2bf(v.z); o.w = f2bf(v.w);
        ((ushort4*)xb)[i] = o;
    }
}

// ---------------------------------------------- transpose f32 (RxC) -> bf16 (CxR)
__global__ void k_transpose_f32_bf16(const float* __restrict__ in,
                                     unsigned short* __restrict__ out,
                                     int R, int C) {
    __shared__ unsigned short Ls[64][68];
    const int c0 = blockIdx.x * 64, r0 = blockIdx.y * 64;
    const int t = threadIdx.x;
    #pragma unroll
    for (int i = 0; i < 4; ++i) {
        int ch = i * 256 + t;              // 1024 float4 chunks
        int r = ch >> 4, c4 = (ch & 15) * 4;
        float4 v = *(const float4*)&in[(size_t)(r0 + r) * C + c0 + c4];
        ushort4 o;
        o.x = f2bf(v.x); o.y = f2bf(v.y); o.z = f2bf(v.z); o.w = f2bf(v.w);
        *(ushort4*)&Ls[r][c4] = o;
    }
    __syncthreads();
    #pragma unroll
    for (int i = 0; i < 2; ++i) {
        int ch = i * 256 + t;              // 512 chunks of 8 bf16
        int rr = ch >> 3, c8 = (ch & 7) * 8;
        unsigned short vals[8];
        #pragma unroll
        for (int j = 0; j < 8; ++j) vals[j] = Ls[c8 + j][rr];
        uint4 pk;
        pk.x = (unsigned)vals[0] | ((unsigned)vals[1] << 16);
        pk.y = (unsigned)vals[2] | ((unsigned)vals[3] << 16);
        pk.z = (unsigned)vals[4] | ((unsigned)vals[5] << 16);
        pk.w = (unsigned)vals[6] | ((unsigned)vals[7] << 16);
        *(uint4*)&out[(size_t)(c0 + rr) * R + r0 + c8] = pk;
    }
}

// ------------------------------------------- 256x128 ring-3 8-wave GEMM
// C[M,N] = A[M,K]*Bt[N,K]^T, bf16 in, f32 acc, bf16 or f32 out.
// BM=256, BN=128, BK=64, 512 thr (8 waves = 4 wm x 2 wn, 64x64/wave).
// LDS ring-3: buf = A[256][64] (16K shorts) | B[128][64] (8K shorts) = 48KB;
// 3 bufs = 144KB -> 1 block/CU. Prefetch distance 2; per tile:
// stage half1(t+2) -> vmcnt(9) -> barrier -> rd(kk0)+16 MFMA ->
// stage half2(t+2) -> rd(kk1)+16 MFMA -> barrier. vmcnt never drains in
// steady state (9 = 6 of t+1 + 3 of t+2-half1). Ring hazard: stage buf
// (t+2)%3 == buf(t-1), whose reads finished before t-1's end barrier.
// Grids: gemm1 16x48=768 = 3 exact CU-rounds; gemm2 16x16=256 = 1 round.
template<int F32OUT>
__launch_bounds__(512, 2)
__global__ void k_gemm8p(const unsigned short* __restrict__ A,
                         const unsigned short* __restrict__ Bt,
                         void* __restrict__ C,
                         int M, int N, int K) {
    __shared__ unsigned short pool[73728];   // 144 KB

    const int tid = threadIdx.x;
    const int wave = tid >> 6, lane = tid & 63;
    const int wm = wave >> 1, wn = wave & 1;
    const int lg = lane >> 4, lr = lane & 15;

    // XCD-aware bijective swizzle (nwg % 8 == 0 for both grids)
    const int nbx = gridDim.x;               // N/128
    const int nwg = nbx * gridDim.y;
    int bid = blockIdx.y * nbx + blockIdx.x;
    int swz = (bid & 7) * (nwg >> 3) + (bid >> 3);
    const int m0 = (swz / nbx) * 256;
    const int n0 = (swz % nbx) * 128;

    // staging geometry: A 2048 chunks (4/thr), B 1024 chunks (2/thr);
    // linear LDS dest (chunk*16B), source col-chunk pre-swizzled (involution).
    int ach[4], bch[2];
    const unsigned short *Ag[4], *Bg[2];
    #pragma unroll
    for (int i = 0; i < 4; ++i) {
        int ch = i * 512 + tid;
        ach[i] = ch;
        int r = ch >> 3, p = ch & 7;
        int csrc = (p ^ (r & 7)) & 7;
        Ag[i] = A + (size_t)(m0 + r) * K + csrc * 8;
    }
    #pragma unroll
    for (int i = 0; i < 2; ++i) {
        int ch = i * 512 + tid;
        bch[i] = ch;
        int r = ch >> 3, p = ch & 7;
        int csrc = (p ^ (r & 7)) & 7;
        Bg[i] = Bt + (size_t)(n0 + r) * K + csrc * 8;
    }

    f32x4 acc[4][4];
    #pragma unroll
    for (int i = 0; i < 4; ++i)
        #pragma unroll
        for (int j = 0; j < 4; ++j) acc[i][j] = f32x4{0.f, 0.f, 0.f, 0.f};

    bf16x8 af[4], bf[4];
    auto rdA = [&](const unsigned short* Cb, int kk) {
        const int cs = ((kk * 4 + lg) ^ (lr & 7)) & 7;
        #pragma unroll
        for (int j = 0; j < 4; ++j)
            af[j] = *(const bf16x8*)&Cb[(wm * 64 + j * 16 + lr) * 64 + cs * 8];
    };
    auto rdB = [&](const unsigned short* Cb, int kk) {
        const int cs = ((kk * 4 + lg) ^ (lr & 7)) & 7;
        #pragma unroll
        for (int n = 0; n < 4; ++n)
            bf[n] = *(const bf16x8*)&Cb[16384 + (wn * 64 + n * 16 + lr) * 64 + cs * 8];
    };
    auto mm16 = [&]() {
        __builtin_amdgcn_s_setprio(1);
        #pragma unroll
        for (int j = 0; j < 4; ++j)
            #pragma unroll
            for (int n = 0; n < 4; ++n)
                acc[j][n] = __builtin_amdgcn_mfma_f32_16x16x32_bf16(
                    af[j], bf[n], acc[j][n], 0, 0, 0);
        __builtin_amdgcn_s_setprio(0);
    };
    auto stageFull = [&](int T, unsigned short* buf) {
        #pragma unroll
        for (int i = 0; i < 4; ++i) gll16(Ag[i] + (size_t)T * 64, buf + ach[i] * 8);
        #pragma unroll
        for (int i = 0; i < 2; ++i) gll16(Bg[i] + (size_t)T * 64, buf + 16384 + bch[i] * 8);
    };
    auto stageH1 = [&](int T, unsigned short* buf) {   // 3 loads
        gll16(Ag[0] + (size_t)T * 64, buf + ach[0] * 8);
        gll16(Ag[1] + (size_t)T * 64, buf + ach[1] * 8);
        gll16(Bg[0] + (size_t)T * 64, buf + 16384 + bch[0] * 8);
    };
    auto stageH2 = [&](int T, unsigned short* buf) {   // 3 loads
        gll16(Ag[2] + (size_t)T * 64, buf + ach[2] * 8);
        gll16(Ag[3] + (size_t)T * 64, buf + ach[3] * 8);
        gll16(Bg[1] + (size_t)T * 64, buf + 16384 + bch[1] * 8);
    };

    const int NT = K >> 6;   // 32

    // prologue: tiles 0,1 -> bufs 0,1 (12 loads in flight)
    stageFull(0, pool);
    stageFull(1, pool + 24576);

    int bt = 0, bs = 2;      // compute buf, stage buf (= (t+2)%3)
    for (int t = 0; t < NT; ++t) {
        unsigned short* Cb = pool + bt * 24576;
        unsigned short* Sb = pool + bs * 24576;
        const bool pre = (t + 2 < NT);
        if (pre) stageH1(t + 2, Sb);
        if (pre)                asm volatile("s_waitcnt vmcnt(9)" ::: "memory");
        else if (t + 1 < NT)    asm volatile("s_waitcnt vmcnt(6)" ::: "memory");
        else                    asm volatile("s_waitcnt vmcnt(0)" ::: "memory");
        __builtin_amdgcn_s_barrier();       // buf bt ready for all waves

        rdA(Cb, 0); rdB(Cb, 0);
        mm16();
        if (pre) stageH2(t + 2, Sb);
        rdA(Cb, 1); rdB(Cb, 1);
        mm16();
        __builtin_amdgcn_s_barrier();       // all reads of buf bt done
        bt = (bt == 2) ? 0 : bt + 1;
        bs = (bs == 2) ? 0 : bs + 1;
    }

    if (F32OUT) {
        // f32 scattered stores cover full 64B lines (16 lanes x 4B)
        #pragma unroll
        for (int j = 0; j < 4; ++j) {
            int row0 = m0 + wm * 64 + j * 16 + lg * 4;
            #pragma unroll
            for (int n = 0; n < 4; ++n) {
                int col = n0 + wn * 64 + n * 16 + lr;
                #pragma unroll
                for (int r = 0; r < 4; ++r)
                    ((float*)C)[(size_t)(row0 + r) * N + col] = acc[j][n][r];
            }
        }
    } else {
        // stage bf16 C-tile [256][128] in LDS (64KB), write coalesced uint4
        unsigned short* Cs = pool;
        #pragma unroll
        for (int j = 0; j < 4; ++j)
            #pragma unroll
            for (int n = 0; n < 4; ++n)
                #pragma unroll
                for (int r = 0; r < 4; ++r)
                    Cs[(wm * 64 + j * 16 + lg * 4 + r) * 128 + wn * 64 + n * 16 + lr] =
                        f2bf(acc[j][n][r]);
        __syncthreads();
        #pragma unroll
        for (int i = 0; i < 8; ++i) {
            int ch = i * 512 + tid;           // 4096 chunks of 8 shorts
            int row = ch >> 4, c8 = (ch & 15) * 8;
            *(uint4*)&((unsigned short*)C)[(size_t)(m0 + row) * N + n0 + c8] =
                *(const uint4*)&Cs[row * 128 + c8];
        }
    }
}

// ------------------------------------------------------- RoPE + LayerNorm (q,k)
__global__ void k_ropeln(const unsigned short* __restrict__ proj,
                         const float* __restrict__ ln_scale,
                         const float* __restrict__ ln_bias,
                         unsigned short* __restrict__ Qh,
                         unsigned short* __restrict__ Kh) {
    const int n = blockIdx.x;
    const int wave = threadIdx.x >> 6, lane = threadIdx.x & 63;
    float inv = expf(-((float)(2 * lane) / 128.0f) * 9.210340371976184f);
    float ang = (float)n * inv;
    float c = cosf(ang), s = sinf(ang);
    const float sc1 = ln_scale[lane], sc2 = ln_scale[lane + 64];
    const float b1 = ln_bias[lane],  b2 = ln_bias[lane + 64];

    for (int r = wave; r < 32; r += 4) {
        int h = r >> 1, qk = r & 1;
        const unsigned short* src = proj + (size_t)n * (3 * EDIM) + qk * EDIM + h * HD;
        float x1 = bf2f(src[lane]), x2 = bf2f(src[lane + 64]);
        float o1 = x1 * c - x2 * s;
        float o2 = x1 * s + x2 * c;
        float sum = o1 + o2, sq = o1 * o1 + o2 * o2;
        #pragma unroll
        for (int d = 1; d < 64; d <<= 1) {
            sum += __shfl_xor(sum, d);
            sq  += __shfl_xor(sq, d);
        }
        float mean = sum * (1.0f / 128.0f);
        float var = sq * (1.0f / 128.0f) - mean * mean;
        float rstd = rsqrtf(var + 1e-5f);
        float y1 = (o1 - mean) * rstd * sc1 + b1;
        float y2 = (o2 - mean) * rstd * sc2 + b2;
        unsigned short* dst = (qk ? Kh : Qh) + ((size_t)h * N_SEQ + n) * HD;
        dst[lane]      = f2bf(y1);
        dst[lane + 64] = f2bf(y2);
    }
}

// ---------------------------------------------------- V transpose: [n][d] -> [d][n]
// Vt with the PV k-permutation baked into each 64-key tile:
// tile position p*8+i  <-  k = 32*(p>>2) + 16*(i>>2) + 4*(p&3) + (i&3)
__global__ void k_vtrans(const unsigned short* __restrict__ proj,
                         unsigned short* __restrict__ Vt) {
    __shared__ unsigned short Ls[64][136];
    const int h = blockIdx.y;
    const int n0 = blockIdx.x * 64;
    const int t = threadIdx.x;
    #pragma unroll
    for (int i = 0; i < 4; ++i) {
        int ch = i * 256 + t;
        int r = ch >> 4, d0 = (ch & 15) * 8;
        uint4 v = *(const uint4*)&proj[(size_t)(n0 + r) * (3 * EDIM) + 2 * EDIM + h * HD + d0];
        *(uint4*)&Ls[r][d0] = v;
    }
    __syncthreads();
    #pragma unroll
    for (int i = 0; i < 4; ++i) {
        int ch = i * 256 + t;
        int d = ch >> 3, p = ch & 7;
        unsigned short vals[8];
        #pragma unroll
        for (int j = 0; j < 8; ++j) {
            int ko = 32 * (p >> 2) + 16 * (j >> 2) + 4 * (p & 3) + (j & 3);
            vals[j] = Ls[ko][d];
        }
        uint4 pk;
        pk.x = (unsigned)vals[0] | ((unsigned)vals[1] << 16);
        pk.y = (unsigned)vals[2] | ((unsigned)vals[3] << 16);
        pk.z = (unsigned)vals[4] | ((unsigned)vals[5] << 16);
        pk.w = (unsigned)vals[6] | ((unsigned)vals[7] << 16);
        *(uint4*)&Vt[((size_t)h * HD + d) * N_SEQ + n0 + p * 8] = pk;
    }
}

// ------------------------------------------------------- polynomial attention
// round-12 version (best measured): 64 q-rows/block, 4 waves = wq x wk
// k-split, in-register P (swapped QK^T + cvt_pk), permuted-Vt b128 B-frags,
// unroll-2 dbuf, vmcnt(8). LPT dispatch: qt descending, b%8 = XCD = h>>1.
__launch_bounds__(256, 2)
__global__ void k_attn(const unsigned short* __restrict__ Qh,
                       const unsigned short* __restrict__ Kh,
                       const unsigned short* __restrict__ Vt,
                       unsigned short* __restrict__ O) {
    // K[2][64][128] | V[2][128][64] = 64 KB; end reused as Xf(36KB)+Cs(16KB)
    __shared__ unsigned short pool[4 * 8192];

    const int t = threadIdx.x;
    const int w = t >> 6, lane = t & 63;
    const int wq = w >> 1, wk = w & 1;
    const int lg = lane >> 4, lr = lane & 15;

    // LPT dispatch: heavy q-tiles first. b&7 = XCD = h>>1 (2 heads/XCD).
    const int b = blockIdx.x;
    const int h = (b & 7) * 2 + ((b >> 3) & 1);
    const int qt = 63 - (b >> 4);
    const int q0 = qt * 64;
    const int qbase = q0 + wq * 32;   // this wave's first q-row
    const int kbase = wk * 32;        // this wave's k-offset within a tile

    // Q fragments (wave's 32 queries x 128 d)
    bf16x8 qf[2][4];
    #pragma unroll
    for (int mi = 0; mi < 2; ++mi)
        #pragma unroll
        for (int kk = 0; kk < 4; ++kk)
            qf[mi][kk] = *(const bf16x8*)&Qh[((size_t)h * N_SEQ + qbase + mi * 16 + lr) * HD + kk * 32 + lg * 8];

    f32x4 acc[2][8];
    #pragma unroll
    for (int i = 0; i < 2; ++i)
        #pragma unroll
        for (int j2 = 0; j2 < 8; ++j2) acc[i][j2] = f32x4{0.f, 0.f, 0.f, 0.f};
    f32x4 accd[2];
    accd[0] = f32x4{0.f, 0.f, 0.f, 0.f};
    accd[1] = f32x4{0.f, 0.f, 0.f, 0.f};

    // ones B-fragment: row-sum lands in output col 0 (k-permutation-invariant)
    bf16x8 onesf;
    {
        short ov = (lr == 0) ? (short)0x3F80 : (short)0;
        #pragma unroll
        for (int j2 = 0; j2 < 8; ++j2) onesf[j2] = ov;
    }

    // staging: per tile K 64x128 (1024 chunks, 4/thr) + V 128x64 (1024, 4/thr)
    int kch[4], vch[4];
    const unsigned short* kg[4];
    const unsigned short* vg[4];
    #pragma unroll
    for (int i = 0; i < 4; ++i) {
        int ch = i * 256 + t;
        kch[i] = ch;
        int r = ch >> 4, p = ch & 15;
        int csrc = (p & 8) | ((p ^ r) & 7);
        kg[i] = Kh + ((size_t)h * N_SEQ + r) * HD + csrc * 8;
    }
    #pragma unroll
    for (int i = 0; i < 4; ++i) {
        int ch = i * 256 + t;
        vch[i] = ch;
        int d = ch >> 3, p2 = ch & 7;
        int c2src = (p2 ^ d) & 7;
        vg[i] = Vt + ((size_t)h * HD + d) * N_SEQ + c2src * 8;
    }

    const int nkb = qt + 1;

    union U8 { unsigned u[4]; bf16x8 v; };

    auto stage = [&](unsigned short* Kn, unsigned short* Vn) {
        #pragma unroll
        for (int i = 0; i < 4; ++i) { gll16(kg[i], Kn + kch[i] * 8); kg[i] += 64 * HD; }
        #pragma unroll
        for (int i = 0; i < 4; ++i) { gll16(vg[i], Vn + vch[i] * 8); vg[i] += 64; }
    };

    auto compute = [&](int k0, const unsigned short* Kc, const unsigned short* Vc) {
        if (k0 + kbase > qbase + 31) return;   // wave's k-half fully masked
        // ---- S^T = K Q^T (swapped): lane holds S[k0+kbase+16nj+4lg+r][qbase+16mi+lr]
        f32x4 sa[2][2];
        #pragma unroll
        for (int i = 0; i < 2; ++i) {
            sa[i][0] = f32x4{0.f, 0.f, 0.f, 0.f};
            sa[i][1] = f32x4{0.f, 0.f, 0.f, 0.f};
        }
        bf16x8 kf[2][4];
        #pragma unroll
        for (int nj = 0; nj < 2; ++nj)
            #pragma unroll
            for (int kk = 0; kk < 4; ++kk) {
                int row = kbase + nj * 16 + lr;
                int c = kk * 4 + lg;
                int cs = (c & 8) | ((c ^ row) & 7);
                kf[nj][kk] = *(const bf16x8*)&Kc[row * 128 + cs * 8];
            }
        __builtin_amdgcn_s_setprio(1);
        #pragma unroll
        for (int kk = 0; kk < 4; ++kk)
            #pragma unroll
            for (int nj = 0; nj < 2; ++nj)
                #pragma unroll
                for (int mi = 0; mi < 2; ++mi)
                    sa[mi][nj] = __builtin_amdgcn_mfma_f32_16x16x32_bf16(
                        kf[nj][kk], qf[mi][kk], sa[mi][nj], 0, 0, 0);
        __builtin_amdgcn_s_setprio(0);

        // ---- mask + ^4 + pack to bf16 pairs in registers
        unsigned wreg[2][2][2];
        const bool nomask = (k0 + kbase + 31 <= qbase);
        #pragma unroll
        for (int mi = 0; mi < 2; ++mi)
            #pragma unroll
            for (int nj = 0; nj < 2; ++nj) {
                float p[4];
                #pragma unroll
                for (int r = 0; r < 4; ++r) {
                    float sv = sa[mi][nj][r];
                    float t2 = sv * sv;
                    p[r] = t2 * t2;
                    if (!nomask) {
                        int gk = k0 + kbase + nj * 16 + lg * 4 + r;
                        int gq = qbase + mi * 16 + lr;
                        p[r] = (gk <= gq) ? p[r] : 0.0f;
                    }
                }
                asm("v_cvt_pk_bf16_f32 %0, %1, %2" : "=v"(wreg[mi][nj][0]) : "v"(p[0]), "v"(p[1]));
                asm("v_cvt_pk_bf16_f32 %0, %1, %2" : "=v"(wreg[mi][nj][1]) : "v"(p[2]), "v"(p[3]));
            }

        // ---- O += P V (k-half), denom += P * ones
        bf16x8 pa[2];
        #pragma unroll
        for (int mi = 0; mi < 2; ++mi) {
            U8 u;
            u.u[0] = wreg[mi][0][0];
            u.u[1] = wreg[mi][0][1];
            u.u[2] = wreg[mi][1][0];
            u.u[3] = wreg[mi][1][1];
            pa[mi] = u.v;
        }
        __builtin_amdgcn_s_setprio(1);
        #pragma unroll
        for (int ni = 0; ni < 8; ++ni) {
            int d = ni * 16 + lr;
            int cs = ((wk * 4 + lg) ^ (d & 7)) & 7;
            bf16x8 vf = *(const bf16x8*)&Vc[d * 64 + cs * 8];
            #pragma unroll
            for (int mi = 0; mi < 2; ++mi)
                acc[mi][ni] = __builtin_amdgcn_mfma_f32_16x16x32_bf16(pa[mi], vf, acc[mi][ni], 0, 0, 0);
        }
        #pragma unroll
        for (int mi = 0; mi < 2; ++mi)
            accd[mi] = __builtin_amdgcn_mfma_f32_16x16x32_bf16(pa[mi], onesf, accd[mi], 0, 0, 0);
        __builtin_amdgcn_s_setprio(0);
    };

    // prologue: stage tile 0 into buf 0
    stage(pool, pool + 16384);
    int kb0 = 0;
    if (nkb & 1) {
        asm volatile("s_waitcnt vmcnt(0)" ::: "memory");
        __builtin_amdgcn_s_barrier();
        compute(0, pool, pool + 16384);
        __builtin_amdgcn_s_barrier();
        if (nkb > 1) stage(pool, pool + 16384);   // tile 1 -> buf0
        kb0 = 1;
    }
    for (int kb = kb0; kb < nkb; kb += 2) {
        stage(pool + 8192, pool + 16384 + 8192);  // tile kb+1 -> buf1
        asm volatile("s_waitcnt vmcnt(8)" ::: "memory");
        __builtin_amdgcn_s_barrier();
        compute(kb * 64, pool, pool + 16384);
        __builtin_amdgcn_s_barrier();
        if (kb + 2 < nkb) {
            stage(pool, pool + 16384);            // tile kb+2 -> buf0
            asm volatile("s_waitcnt vmcnt(8)" ::: "memory");
        } else {
            asm volatile("s_waitcnt vmcnt(0)" ::: "memory");
        }
        __builtin_amdgcn_s_barrier();
        compute((kb + 1) * 64, pool + 8192, pool + 16384 + 8192);
        __builtin_amdgcn_s_barrier();
    }

    // ---- combine wk halves (f32 add via LDS, slot-major conflict-free) ----
    asm volatile("s_waitcnt vmcnt(0)" ::: "memory");   // drain stray prefetches
    __syncthreads();
    float* Xf = (float*)pool;                 // [wq][18 slots][64 lanes][4] f32
    const int xbase = wq * 4608 + lane * 4;
    if (wk == 1) {
        #pragma unroll
        for (int mi = 0; mi < 2; ++mi) {
            #pragma unroll
            for (int ni = 0; ni < 8; ++ni)
                *(f32x4*)&Xf[xbase + (mi * 8 + ni) * 256] = acc[mi][ni];
            *(f32x4*)&Xf[xbase + (16 + mi) * 256] = accd[mi];
        }
    }
    __syncthreads();
    unsigned short* Cs = pool + 20480;        // [64][128] bf16, disjoint from Xf
    if (wk == 0) {
        #pragma unroll
        for (int mi = 0; mi < 2; ++mi) {
            #pragma unroll
            for (int ni = 0; ni < 8; ++ni) {
                f32x4 o = *(const f32x4*)&Xf[xbase + (mi * 8 + ni) * 256];
                acc[mi][ni][0] += o[0]; acc[mi][ni][1] += o[1];
                acc[mi][ni][2] += o[2]; acc[mi][ni][3] += o[3];
            }
            f32x4 od = *(const f32x4*)&Xf[xbase + (16 + mi) * 256];
            accd[mi][0] += od[0]; accd[mi][1] += od[1];
            accd[mi][2] += od[2]; accd[mi][3] += od[3];
        }
        // divide + stage bf16 tile
        #pragma unroll
        for (int mi = 0; mi < 2; ++mi) {
            #pragma unroll
            for (int r = 0; r < 4; ++r) {
                float dv = __shfl(accd[mi][r], lane & 48);  // col 0 in lane lg*16
                float rinv = 1.0f / dv;
                int rw = wq * 32 + mi * 16 + lg * 4 + r;
                #pragma unroll
                for (int ni = 0; ni < 8; ++ni)
                    Cs[rw * 128 + ni * 16 + lr] = f2bf(acc[mi][ni][r] * rinv);
            }
        }
    }
    __syncthreads();
    #pragma unroll
    for (int i = 0; i < 4; ++i) {
        int ch = i * 256 + t;                 // 1024 chunks of 8 shorts
        int row = ch >> 4, c8 = (ch & 15) * 8;
        *(uint4*)&O[(size_t)(q0 + row) * EDIM + h * HD + c8] = *(const uint4*)&Cs[row * 128 + c8];
    }
}

// ---------------------------------------------------------------- launch
extern "C" void kernel_launch(void* const* d_in, const int* in_sizes, int n_in,
                              void* d_out, int out_size, void* d_ws, size_t ws_size,
                              hipStream_t stream) {
    const float* x        = (const float*)d_in[0];
    const float* w_qkv    = (const float*)d_in[1];
    const float* w_out    = (const float*)d_in[2];
    const float* ln_scale = (const float*)d_in[3];
    const float* ln_bias  = (const float*)d_in[4];

    if (ws_size < 134217728u) return;  // need 128 MiB

    char* ws = (char*)d_ws;
    unsigned short* xb    = (unsigned short*)(ws);              // 16 MiB; reused as attnO
    unsigned short* wqkvT = (unsigned short*)(ws + 16777216);   // 24 MiB; reused as Qh
    unsigned short* woutT = (unsigned short*)(ws + 41943040);   //  8 MiB
    unsigned short* proj  = (unsigned short*)(ws + 50331648);   // 48 MiB
    unsigned short* Kh    = (unsigned short*)(ws + 100663296);  // 16 MiB
    unsigned short* Vt    = (unsigned short*)(ws + 117440512);  // 16 MiB
    unsigned short* Qh    = wqkvT;   // alias: w_qkvT dead after GEMM1
    unsigned short* attnO = xb;      // alias: xb dead after GEMM1

    k_convert_x<<<2048, 256, 0, stream>>>(x, xb, (N_SEQ * EDIM) / 4);
    k_transpose_f32_bf16<<<dim3(3 * EDIM / 64, EDIM / 64), 256, 0, stream>>>(w_qkv, wqkvT, EDIM, 3 * EDIM);
    k_transpose_f32_bf16<<<dim3(EDIM / 64, EDIM / 64), 256, 0, stream>>>(w_out, woutT, EDIM, EDIM);
    k_gemm8p<0><<<dim3(3 * EDIM / 128, N_SEQ / 256), 512, 0, stream>>>(xb, wqkvT, proj, N_SEQ, 3 * EDIM, EDIM);
    k_ropeln<<<N_SEQ, 256, 0, stream>>>(proj, ln_scale, ln_bias, Qh, Kh);
    k_vtrans<<<dim3(N_SEQ / 64, NH), 256, 0, stream>>>(proj, Vt);
    k_attn<<<1024, 256, 0, stream>>>(Qh, Kh, Vt, attnO);
    k_gemm8p<1><<<dim3(EDIM / 128, N_SEQ / 256), 512, 0, stream>>>(attnO, woutT, (float*)d_out, N_SEQ, EDIM, EDIM);
}